// Round 1
// baseline (450.473 us; speedup 1.0000x reference)
//
#include <hip/hip_runtime.h>
#include <hip/hip_bf16.h>

// Problem constants
#define HW_   2304     // 48*48
#define WDIM  48
#define CDIM  128
#define NTOK  18432    // 8 * 2304
#define DHW   9216     // 4*2304 (c-stride in x)
#define BCDHW 1179648  // 128*4*2304 (b-stride in x)

// ---------------- transpose in: x(B,C,D,H,W) -> t0(BD,HW,C) ----------------
__global__ __launch_bounds__(256) void k_transpose_in(const float* __restrict__ x,
                                                      float* __restrict__ t0) {
  __shared__ float tile[32][33];
  int bd = blockIdx.z; int b = bd >> 2, d = bd & 3;
  int s0 = blockIdx.x * 32, c0 = blockIdx.y * 32;
  int tx = threadIdx.x & 31, ty = threadIdx.x >> 5;
  size_t xbase = (size_t)b * BCDHW + (size_t)d * HW_;
#pragma unroll
  for (int i = 0; i < 4; i++) {
    int c = c0 + ty + i * 8;
    tile[ty + i * 8][tx] = x[xbase + (size_t)c * DHW + s0 + tx];
  }
  __syncthreads();
#pragma unroll
  for (int i = 0; i < 4; i++) {
    int s = s0 + ty + i * 8;
    t0[((size_t)bd * HW_ + s) * CDIM + c0 + tx] = tile[tx][ty + i * 8];
  }
}

// ---------------- transpose out: t2(BD,HW,C) -> out(B,C,D,H,W) ----------------
__global__ __launch_bounds__(256) void k_transpose_out(const float* __restrict__ t2,
                                                       float* __restrict__ out) {
  __shared__ float tile[32][33];
  int bd = blockIdx.z; int b = bd >> 2, d = bd & 3;
  int s0 = blockIdx.x * 32, c0 = blockIdx.y * 32;
  int tx = threadIdx.x & 31, ty = threadIdx.x >> 5;
#pragma unroll
  for (int i = 0; i < 4; i++) {
    int s = s0 + ty + i * 8;
    tile[ty + i * 8][tx] = t2[((size_t)bd * HW_ + s) * CDIM + c0 + tx];
  }
  __syncthreads();
  size_t obase = (size_t)b * BCDHW + (size_t)d * HW_;
#pragma unroll
  for (int i = 0; i < 4; i++) {
    int c = c0 + ty + i * 8;
    out[obase + (size_t)c * DHW + s0 + tx] = tile[tx][ty + i * 8];
  }
}

// ---------------- LayerNorm: one wave (64 lanes) per token, 2 elems/lane ----------------
__global__ __launch_bounds__(256) void k_ln(const float* __restrict__ in,
                                            const float* __restrict__ w,
                                            const float* __restrict__ b,
                                            float* __restrict__ out) {
  int tok = blockIdx.x * 4 + (threadIdx.x >> 6);
  int lane = threadIdx.x & 63;
  float2 v = *(const float2*)&in[(size_t)tok * CDIM + lane * 2];
  float s = v.x + v.y;
#pragma unroll
  for (int m = 1; m < 64; m <<= 1) s += __shfl_xor(s, m);
  float mean = s * 0.0078125f;
  float dx = v.x - mean, dy = v.y - mean;
  float ss = dx * dx + dy * dy;
#pragma unroll
  for (int m = 1; m < 64; m <<= 1) ss += __shfl_xor(ss, m);
  float rs = rsqrtf(ss * 0.0078125f + 1e-5f);
  float2 o;
  o.x = dx * rs * w[lane * 2] + b[lane * 2];
  o.y = dy * rs * w[lane * 2 + 1] + b[lane * 2 + 1];
  *(float2*)&out[(size_t)tok * CDIM + lane * 2] = o;
}

// ---------------- generic fp32 GEMM: C = act(A @ W^T + bias) (+res) ----------------
// A: (M,K) row-major, W: (N,K) row-major. BM=BN=64, BK=16, 256 thr, 4x4/thread.
__device__ __forceinline__ float gelu_exact(float x) {
  return 0.5f * x * (1.0f + erff(x * 0.7071067811865475f));
}

template <int ACT, int RES>
__global__ __launch_bounds__(256) void k_gemm(const float* __restrict__ A,
                                              const float* __restrict__ Wt,
                                              const float* __restrict__ bias,
                                              const float* __restrict__ res,
                                              float* __restrict__ C,
                                              int M, int N, int K) {
  __shared__ __align__(16) float As[16][68];
  __shared__ __align__(16) float Bs[16][68];
  int tid = threadIdx.x;
  int row0 = blockIdx.x * 64, col0 = blockIdx.y * 64;
  int tx = tid & 15, ty = tid >> 4;
  int lr = tid >> 2;            // 0..63 row within tile
  int lk = (tid & 3) * 4;       // k quad 0,4,8,12

  float acc[4][4];
#pragma unroll
  for (int i = 0; i < 4; i++)
#pragma unroll
    for (int j = 0; j < 4; j++) acc[i][j] = 0.f;

  for (int kt = 0; kt < K; kt += 16) {
    float4 av = *(const float4*)&A[(size_t)(row0 + lr) * K + kt + lk];
    float4 bv = *(const float4*)&Wt[(size_t)(col0 + lr) * K + kt + lk];
    As[lk + 0][lr] = av.x; As[lk + 1][lr] = av.y; As[lk + 2][lr] = av.z; As[lk + 3][lr] = av.w;
    Bs[lk + 0][lr] = bv.x; Bs[lk + 1][lr] = bv.y; Bs[lk + 2][lr] = bv.z; Bs[lk + 3][lr] = bv.w;
    __syncthreads();
#pragma unroll
    for (int k = 0; k < 16; k++) {
      float4 a4 = *(const float4*)&As[k][ty * 4];
      float4 b4 = *(const float4*)&Bs[k][tx * 4];
      float a[4] = {a4.x, a4.y, a4.z, a4.w};
      float b[4] = {b4.x, b4.y, b4.z, b4.w};
#pragma unroll
      for (int i = 0; i < 4; i++)
#pragma unroll
        for (int j = 0; j < 4; j++) acc[i][j] = fmaf(a[i], b[j], acc[i][j]);
    }
    __syncthreads();
  }

#pragma unroll
  for (int i = 0; i < 4; i++) {
    int r = row0 + ty * 4 + i;
    int cb = col0 + tx * 4;
    float o[4];
#pragma unroll
    for (int j = 0; j < 4; j++) {
      o[j] = acc[i][j] + bias[cb + j];
      if (ACT == 1) o[j] = gelu_exact(o[j]);
    }
    if (RES) {
      float4 rv = *(const float4*)&res[(size_t)r * N + cb];
      o[0] += rv.x; o[1] += rv.y; o[2] += rv.z; o[3] += rv.w;
    }
    float4 ov = make_float4(o[0], o[1], o[2], o[3]);
    *(float4*)&C[(size_t)r * N + cb] = ov;
  }
}

// ---------------- 7x7 neighborhood attention, one token per block ----------------
// qkv row layout: [q(n0 d0..31, n1, n2, n3) | k(...) | v(...)]  (384 floats)
__global__ __launch_bounds__(128) void k_natt(const float* __restrict__ qkv,
                                              const float* __restrict__ rpb,
                                              float* __restrict__ out) {
  __shared__ float sc[4][64];
  __shared__ int nbr[49];
  int tok = blockIdx.x;
  int bd = tok / HW_; int sp = tok - bd * HW_;
  int h = sp / WDIM; int w = sp - h * WDIM;
  int t = threadIdx.x; int n = t >> 5; int dl = t & 31;
  int sh = h - 3; sh = sh < 0 ? 0 : (sh > 41 ? 41 : sh);
  int sw = w - 3; sw = sw < 0 ? 0 : (sw > 41 ? 41 : sw);
  if (t < 49) {
    int i = t / 7, j = t - (t / 7) * 7;
    nbr[t] = (bd * HW_ + (sh + i) * WDIM + (sw + j)) * 384;
  }
  float q = qkv[(size_t)tok * 384 + t] * 0.17677669529663687f; // 1/sqrt(32)
  __syncthreads();

  for (int jj = 0; jj < 49; ++jj) {
    float kv = qkv[nbr[jj] + 128 + t];
    float p = q * kv;
    p += __shfl_xor(p, 1); p += __shfl_xor(p, 2); p += __shfl_xor(p, 4);
    p += __shfl_xor(p, 8); p += __shfl_xor(p, 16);
    if (dl == 0) {
      int i = jj / 7, j = jj - (jj / 7) * 7;
      sc[n][jj] = p + rpb[n * 169 + (sh + i - h + 6) * 13 + (sw + j - w + 6)];
    }
  }
  __syncthreads();

  // softmax over 49 per head (32-lane subgroup)
  float a = sc[n][dl];                              // dl < 32 <= 48 valid
  float b2 = (dl < 17) ? sc[n][dl + 32] : -1e30f;   // dl+32 < 49
  float mx = fmaxf(a, b2);
  mx = fmaxf(mx, __shfl_xor(mx, 1));  mx = fmaxf(mx, __shfl_xor(mx, 2));
  mx = fmaxf(mx, __shfl_xor(mx, 4));  mx = fmaxf(mx, __shfl_xor(mx, 8));
  mx = fmaxf(mx, __shfl_xor(mx, 16));
  float ea = expf(a - mx);
  float eb = (dl < 17) ? expf(b2 - mx) : 0.f;
  float sm = ea + eb;
  sm += __shfl_xor(sm, 1); sm += __shfl_xor(sm, 2); sm += __shfl_xor(sm, 4);
  sm += __shfl_xor(sm, 8); sm += __shfl_xor(sm, 16);
  float inv = 1.f / sm;
  sc[n][dl] = ea * inv;
  if (dl < 17) sc[n][dl + 32] = eb * inv;
  __syncthreads();

  float acc = 0.f;
  for (int jj = 0; jj < 49; ++jj) acc += sc[n][jj] * qkv[nbr[jj] + 256 + t];
  out[(size_t)tok * CDIM + t] = acc;
}

extern "C" void kernel_launch(void* const* d_in, const int* in_sizes, int n_in,
                              void* d_out, int out_size, void* d_ws, size_t ws_size,
                              hipStream_t stream) {
  const float* x     = (const float*)d_in[0];
  const float* n1w   = (const float*)d_in[1];
  const float* n1b   = (const float*)d_in[2];
  const float* qkvw  = (const float*)d_in[3];
  const float* qkvb  = (const float*)d_in[4];
  const float* rpb   = (const float*)d_in[5];
  const float* projw = (const float*)d_in[6];
  const float* projb = (const float*)d_in[7];
  const float* n2w   = (const float*)d_in[8];
  const float* n2b   = (const float*)d_in[9];
  const float* fc1w  = (const float*)d_in[10];
  const float* fc1b  = (const float*)d_in[11];
  const float* fc2w  = (const float*)d_in[12];
  const float* fc2b  = (const float*)d_in[13];

  float* ws   = (float*)d_ws;
  float* t0   = ws;                  // 2,359,296
  float* nbuf = ws + 2359296;        // LN out; reused for t2
  float* qkv  = ws + 4718592;        // 7,077,888; reused for h1
  float* attn = ws + 11796480;       // 2,359,296
  float* t1   = ws + 14155776;       // 2,359,296
  float* h1   = qkv;
  float* t2   = nbuf;

  k_transpose_in<<<dim3(72, 4, 8), 256, 0, stream>>>(x, t0);
  k_ln<<<NTOK / 4, 256, 0, stream>>>(t0, n1w, n1b, nbuf);
  k_gemm<0, 0><<<dim3(NTOK / 64, 6), 256, 0, stream>>>(nbuf, qkvw, qkvb, nullptr, qkv,
                                                       NTOK, 384, 128);
  k_natt<<<NTOK, 128, 0, stream>>>(qkv, rpb, attn);
  k_gemm<0, 1><<<dim3(NTOK / 64, 2), 256, 0, stream>>>(attn, projw, projb, t0, t1,
                                                       NTOK, 128, 128);
  k_ln<<<NTOK / 4, 256, 0, stream>>>(t1, n2w, n2b, nbuf);
  k_gemm<1, 0><<<dim3(NTOK / 64, 4), 256, 0, stream>>>(nbuf, fc1w, fc1b, nullptr, h1,
                                                       NTOK, 256, 128);
  k_gemm<0, 1><<<dim3(NTOK / 64, 2), 256, 0, stream>>>(h1, fc2w, fc2b, t1, t2,
                                                       NTOK, 128, 256);
  k_transpose_out<<<dim3(72, 4, 8), 256, 0, stream>>>(t2, (float*)d_out);
}

// Round 2
// 234.568 us; speedup vs baseline: 1.9204x; 1.9204x over previous
//
#include <hip/hip_runtime.h>
#include <hip/hip_bf16.h>

#define HW_   2304
#define WDIM  48
#define CDIM  128
#define NTOK  18432
#define DHW   9216
#define BCDHW 1179648

typedef __attribute__((ext_vector_type(8))) short short8;
typedef __attribute__((ext_vector_type(4))) float f32x4;

// ---------------- transpose in: x(B,C,D,H,W) -> t0(BD,HW,C) ----------------
__global__ __launch_bounds__(256) void k_transpose_in(const float* __restrict__ x,
                                                      float* __restrict__ t0) {
  __shared__ float tile[32][33];
  int bd = blockIdx.z; int b = bd >> 2, d = bd & 3;
  int s0 = blockIdx.x * 32, c0 = blockIdx.y * 32;
  int tx = threadIdx.x & 31, ty = threadIdx.x >> 5;
  size_t xbase = (size_t)b * BCDHW + (size_t)d * HW_;
#pragma unroll
  for (int i = 0; i < 4; i++) {
    int c = c0 + ty + i * 8;
    tile[ty + i * 8][tx] = x[xbase + (size_t)c * DHW + s0 + tx];
  }
  __syncthreads();
#pragma unroll
  for (int i = 0; i < 4; i++) {
    int s = s0 + ty + i * 8;
    t0[((size_t)bd * HW_ + s) * CDIM + c0 + tx] = tile[tx][ty + i * 8];
  }
}

// ---------------- transpose out ----------------
__global__ __launch_bounds__(256) void k_transpose_out(const float* __restrict__ t2,
                                                       float* __restrict__ out) {
  __shared__ float tile[32][33];
  int bd = blockIdx.z; int b = bd >> 2, d = bd & 3;
  int s0 = blockIdx.x * 32, c0 = blockIdx.y * 32;
  int tx = threadIdx.x & 31, ty = threadIdx.x >> 5;
#pragma unroll
  for (int i = 0; i < 4; i++) {
    int s = s0 + ty + i * 8;
    tile[ty + i * 8][tx] = t2[((size_t)bd * HW_ + s) * CDIM + c0 + tx];
  }
  __syncthreads();
  size_t obase = (size_t)b * BCDHW + (size_t)d * HW_;
#pragma unroll
  for (int i = 0; i < 4; i++) {
    int c = c0 + ty + i * 8;
    out[obase + (size_t)c * DHW + s0 + tx] = tile[tx][ty + i * 8];
  }
}

// ---------------- weights fp32 -> bf16 (once per launch) ----------------
__global__ __launch_bounds__(256) void k_w2bf(const float* __restrict__ w0,
                                              const float* __restrict__ w1,
                                              const float* __restrict__ w2,
                                              const float* __restrict__ w3,
                                              __hip_bfloat16* __restrict__ out) {
  int i = blockIdx.x * 256 + threadIdx.x;  // 131072 total
  float v;
  if (i < 49152) v = w0[i];
  else if (i < 65536) v = w1[i - 49152];
  else if (i < 98304) v = w2[i - 65536];
  else v = w3[i - 98304];
  out[i] = __float2bfloat16(v);
}

// ---------------- LayerNorm: one wave per token, bf16 out ----------------
__global__ __launch_bounds__(256) void k_ln(const float* __restrict__ in,
                                            const float* __restrict__ w,
                                            const float* __restrict__ b,
                                            __hip_bfloat16* __restrict__ out) {
  int tok = blockIdx.x * 4 + (threadIdx.x >> 6);
  int lane = threadIdx.x & 63;
  float2 v = *(const float2*)&in[(size_t)tok * CDIM + lane * 2];
  float s = v.x + v.y;
#pragma unroll
  for (int m = 1; m < 64; m <<= 1) s += __shfl_xor(s, m);
  float mean = s * 0.0078125f;
  float dx = v.x - mean, dy = v.y - mean;
  float ss = dx * dx + dy * dy;
#pragma unroll
  for (int m = 1; m < 64; m <<= 1) ss += __shfl_xor(ss, m);
  float rs = rsqrtf(ss * 0.0078125f + 1e-5f);
  __hip_bfloat162 h;
  h.x = __float2bfloat16(dx * rs * w[lane * 2] + b[lane * 2]);
  h.y = __float2bfloat16(dy * rs * w[lane * 2 + 1] + b[lane * 2 + 1]);
  *(__hip_bfloat162*)&out[(size_t)tok * CDIM + lane * 2] = h;
}

// ---------------- bf16 MFMA GEMM: out = act(A @ W^T + bias) (+res) ----------------
// A:(M,K) bf16 row-major, W:(N,K) bf16 row-major. Block=256 (4 waves), each wave
// owns a 64x64 output tile; no LDS, frags loaded straight from global.
template <int ACT, int RES, int OUTBF>
__global__ __launch_bounds__(256) void k_gemm(const __hip_bfloat16* __restrict__ A,
                                              const __hip_bfloat16* __restrict__ W,
                                              const float* __restrict__ bias,
                                              const float* __restrict__ res,
                                              float* __restrict__ outF,
                                              __hip_bfloat16* __restrict__ outB,
                                              int M, int N, int K) {
  int wave = threadIdx.x >> 6, lane = threadIdx.x & 63;
  int m_base = blockIdx.x * 256 + wave * 64;
  int n_base = blockIdx.y * 64;
  int r = lane & 15, kg = lane >> 4;

  f32x4 acc[4][4] = {};
  for (int kt = 0; kt < K; kt += 32) {
    short8 a[4], b[4];
    const __hip_bfloat16* ap = A + (size_t)(m_base + r) * K + kt + kg * 8;
    const __hip_bfloat16* bp = W + (size_t)(n_base + r) * K + kt + kg * 8;
#pragma unroll
    for (int i = 0; i < 4; i++) a[i] = *(const short8*)(ap + (size_t)i * 16 * K);
#pragma unroll
    for (int i = 0; i < 4; i++) b[i] = *(const short8*)(bp + (size_t)i * 16 * K);
#pragma unroll
    for (int mi = 0; mi < 4; mi++)
#pragma unroll
      for (int ni = 0; ni < 4; ni++)
        acc[mi][ni] = __builtin_amdgcn_mfma_f32_16x16x32_bf16(a[mi], b[ni], acc[mi][ni], 0, 0, 0);
  }

  // epilogue: C row = (lane>>4)*4 + q, col = lane&15
#pragma unroll
  for (int ni = 0; ni < 4; ni++) {
    int c = n_base + ni * 16 + r;
    float bs = bias[c];
#pragma unroll
    for (int mi = 0; mi < 4; mi++) {
#pragma unroll
      for (int q = 0; q < 4; q++) {
        int rr = m_base + mi * 16 + kg * 4 + q;
        float o = acc[mi][ni][q] + bs;
        if (ACT) o = 0.5f * o * (1.0f + erff(o * 0.7071067811865475f));
        if (RES) o += res[(size_t)rr * N + c];
        if (OUTBF) outB[(size_t)rr * N + c] = __float2bfloat16(o);
        else outF[(size_t)rr * N + c] = o;
      }
    }
  }
}

// ---------------- 7x7 neighborhood attention: one wave per token ----------------
// qkv row: [q(4 heads x 32) | k | v] = 384 fp32. Output bf16 (NTOK,128).
__global__ __launch_bounds__(256) void k_natt(const float* __restrict__ qkv,
                                              const float* __restrict__ rpb,
                                              __hip_bfloat16* __restrict__ out) {
  __shared__ float sQ[4][128];
  __shared__ float sS[4][200];
  __shared__ int sNbr[4][52];
  int w = threadIdx.x >> 6, ln = threadIdx.x & 63;
  int tok = blockIdx.x * 4 + w;
  int bd = tok / HW_; int sp = tok - bd * HW_;
  int h = sp / WDIM; int wq = sp - h * WDIM;
  int sh = h - 3; sh = sh < 0 ? 0 : (sh > 41 ? 41 : sh);
  int sw = wq - 3; sw = sw < 0 ? 0 : (sw > 41 ? 41 : sw);

  if (ln < 49) {
    int i = ln / 7, j = ln - i * 7;
    sNbr[w][ln] = (bd * HW_ + (sh + i) * WDIM + (sw + j)) * 384;
  }
  float2 q2 = *(const float2*)&qkv[(size_t)tok * 384 + ln * 2];
  sQ[w][ln * 2] = q2.x * 0.17677669529663687f;
  sQ[w][ln * 2 + 1] = q2.y * 0.17677669529663687f;
  __syncthreads();

  // scores: lane p handles (head n, nbr j) pairs p, p+64, p+128, p+192
  for (int p = ln; p < 196; p += 64) {
    int n = p / 49, j = p - n * 49;
    const float* kp = qkv + sNbr[w][j] + 128 + n * 32;
    const float* qp = &sQ[w][n * 32];
    float acc = 0.f;
#pragma unroll
    for (int dd = 0; dd < 8; dd++) {
      float4 kv = *(const float4*)&kp[dd * 4];
      float4 qv = *(const float4*)&qp[dd * 4];
      acc = fmaf(kv.x, qv.x, acc); acc = fmaf(kv.y, qv.y, acc);
      acc = fmaf(kv.z, qv.z, acc); acc = fmaf(kv.w, qv.w, acc);
    }
    int i = j / 7, jj = j - i * 7;
    sS[w][n * 49 + j] = acc + rpb[n * 169 + (sh + i - h + 6) * 13 + (sw + jj - wq + 6)];
  }
  __syncthreads();

  // softmax per head: 16 lanes per head, 49 scores
  {
    int n = ln >> 4, sub = ln & 15;
    float v0 = sS[w][n * 49 + sub];
    float v1 = sS[w][n * 49 + sub + 16];
    float v2 = sS[w][n * 49 + sub + 32];
    float v3 = (sub == 0) ? sS[w][n * 49 + 48] : -1e30f;
    float mx = fmaxf(fmaxf(v0, v1), fmaxf(v2, v3));
    mx = fmaxf(mx, __shfl_xor(mx, 1)); mx = fmaxf(mx, __shfl_xor(mx, 2));
    mx = fmaxf(mx, __shfl_xor(mx, 4)); mx = fmaxf(mx, __shfl_xor(mx, 8));
    float e0 = expf(v0 - mx), e1 = expf(v1 - mx), e2 = expf(v2 - mx);
    float e3 = (sub == 0) ? expf(v3 - mx) : 0.f;
    float s = e0 + e1 + e2 + e3;
    s += __shfl_xor(s, 1); s += __shfl_xor(s, 2);
    s += __shfl_xor(s, 4); s += __shfl_xor(s, 8);
    float inv = 1.f / s;
    sS[w][n * 49 + sub] = e0 * inv;
    sS[w][n * 49 + sub + 16] = e1 * inv;
    sS[w][n * 49 + sub + 32] = e2 * inv;
    if (sub == 0) sS[w][n * 49 + 48] = e3 * inv;
  }
  __syncthreads();

  // PV: lane owns channels 2*ln, 2*ln+1 (head n = ln>>4)
  {
    int n = ln >> 4;
    int c2 = ln * 2;
    float ax = 0.f, ay = 0.f;
#pragma unroll 7
    for (int j = 0; j < 49; j++) {
      float wgt = sS[w][n * 49 + j];
      float2 v = *(const float2*)&qkv[sNbr[w][j] + 256 + c2];
      ax = fmaf(wgt, v.x, ax); ay = fmaf(wgt, v.y, ay);
    }
    __hip_bfloat162 o;
    o.x = __float2bfloat16(ax); o.y = __float2bfloat16(ay);
    *(__hip_bfloat162*)&out[(size_t)tok * CDIM + c2] = o;
  }
}

extern "C" void kernel_launch(void* const* d_in, const int* in_sizes, int n_in,
                              void* d_out, int out_size, void* d_ws, size_t ws_size,
                              hipStream_t stream) {
  const float* x     = (const float*)d_in[0];
  const float* n1w   = (const float*)d_in[1];
  const float* n1b   = (const float*)d_in[2];
  const float* qkvw  = (const float*)d_in[3];
  const float* qkvb  = (const float*)d_in[4];
  const float* rpb   = (const float*)d_in[5];
  const float* projw = (const float*)d_in[6];
  const float* projb = (const float*)d_in[7];
  const float* n2w   = (const float*)d_in[8];
  const float* n2b   = (const float*)d_in[9];
  const float* fc1w  = (const float*)d_in[10];
  const float* fc1b  = (const float*)d_in[11];
  const float* fc2w  = (const float*)d_in[12];
  const float* fc2b  = (const float*)d_in[13];

  char* wsb = (char*)d_ws;
  float* t0            = (float*)wsb;                       // 9.44 MB
  float* t1            = (float*)(wsb + 9437184);           // 9.44 MB
  float* qkv           = (float*)(wsb + 18874368);          // 28.3 MB
  __hip_bfloat16* h1b  = (__hip_bfloat16*)(wsb + 18874368); // reuses qkv
  float* t2            = (float*)(wsb + 28311552);          // reuses qkv
  __hip_bfloat16* lnb  = (__hip_bfloat16*)(wsb + 47185920); // 4.72 MB
  __hip_bfloat16* attb = (__hip_bfloat16*)(wsb + 51904512); // 4.72 MB
  __hip_bfloat16* wbf  = (__hip_bfloat16*)(wsb + 56623104); // 0.26 MB

  k_w2bf<<<512, 256, 0, stream>>>(qkvw, projw, fc1w, fc2w, wbf);
  k_transpose_in<<<dim3(72, 4, 8), 256, 0, stream>>>(x, t0);
  k_ln<<<NTOK / 4, 256, 0, stream>>>(t0, n1w, n1b, lnb);
  k_gemm<0, 0, 0><<<dim3(72, 6), 256, 0, stream>>>(lnb, wbf, qkvb, nullptr,
                                                   qkv, nullptr, NTOK, 384, 128);
  k_natt<<<NTOK / 4, 256, 0, stream>>>(qkv, rpb, attb);
  k_gemm<0, 1, 0><<<dim3(72, 2), 256, 0, stream>>>(attb, wbf + 49152, projb, t0,
                                                   t1, nullptr, NTOK, 128, 128);
  k_ln<<<NTOK / 4, 256, 0, stream>>>(t1, n2w, n2b, lnb);
  k_gemm<1, 0, 1><<<dim3(72, 4), 256, 0, stream>>>(lnb, wbf + 65536, fc1b, nullptr,
                                                   nullptr, h1b, NTOK, 256, 128);
  k_gemm<0, 1, 0><<<dim3(72, 2), 256, 0, stream>>>(h1b, wbf + 98304, fc2b, t1,
                                                   t2, nullptr, NTOK, 128, 256);
  k_transpose_out<<<dim3(72, 4, 8), 256, 0, stream>>>(t2, (float*)d_out);
}

// Round 3
// 164.264 us; speedup vs baseline: 2.7424x; 1.4280x over previous
//
#include <hip/hip_runtime.h>
#include <hip/hip_bf16.h>

#define HW_   2304
#define WDIM  48
#define CDIM  128
#define NTOK  18432
#define DHW   9216
#define BCDHW 1179648

typedef __attribute__((ext_vector_type(8))) short short8;
typedef __attribute__((ext_vector_type(4))) short sh4;
typedef __attribute__((ext_vector_type(4))) float f32x4;
typedef __attribute__((ext_vector_type(4))) unsigned short us4;

__device__ __forceinline__ unsigned short f2bf(float f) {
  union { float f; unsigned u; } v; v.f = f;
  unsigned r = v.u + 0x7FFFu + ((v.u >> 16) & 1u);
  return (unsigned short)(r >> 16);
}
__device__ __forceinline__ float bf2f(unsigned short b) {
  union { unsigned u; float f; } v; v.u = ((unsigned)b) << 16; return v.f;
}

// ---------------- transpose in: x(B,C,D,H,W) -> t0(BD,HW,C) ----------------
__global__ __launch_bounds__(256) void k_transpose_in(const float* __restrict__ x,
                                                      float* __restrict__ t0) {
  __shared__ float tile[32][33];
  int bd = blockIdx.z; int b = bd >> 2, d = bd & 3;
  int s0 = blockIdx.x * 32, c0 = blockIdx.y * 32;
  int tx = threadIdx.x & 31, ty = threadIdx.x >> 5;
  size_t xbase = (size_t)b * BCDHW + (size_t)d * HW_;
#pragma unroll
  for (int i = 0; i < 4; i++) {
    int c = c0 + ty + i * 8;
    tile[ty + i * 8][tx] = x[xbase + (size_t)c * DHW + s0 + tx];
  }
  __syncthreads();
#pragma unroll
  for (int i = 0; i < 4; i++) {
    int s = s0 + ty + i * 8;
    t0[((size_t)bd * HW_ + s) * CDIM + c0 + tx] = tile[tx][ty + i * 8];
  }
}

// ---------------- transpose out ----------------
__global__ __launch_bounds__(256) void k_transpose_out(const float* __restrict__ t2,
                                                       float* __restrict__ out) {
  __shared__ float tile[32][33];
  int bd = blockIdx.z; int b = bd >> 2, d = bd & 3;
  int s0 = blockIdx.x * 32, c0 = blockIdx.y * 32;
  int tx = threadIdx.x & 31, ty = threadIdx.x >> 5;
#pragma unroll
  for (int i = 0; i < 4; i++) {
    int s = s0 + ty + i * 8;
    tile[ty + i * 8][tx] = t2[((size_t)bd * HW_ + s) * CDIM + c0 + tx];
  }
  __syncthreads();
  size_t obase = (size_t)b * BCDHW + (size_t)d * HW_;
#pragma unroll
  for (int i = 0; i < 4; i++) {
    int c = c0 + ty + i * 8;
    out[obase + (size_t)c * DHW + s0 + tx] = tile[tx][ty + i * 8];
  }
}

// ---------------- weights fp32 -> bf16 ----------------
__global__ __launch_bounds__(256) void k_w2bf(const float* __restrict__ w0,
                                              const float* __restrict__ w1,
                                              const float* __restrict__ w2,
                                              const float* __restrict__ w3,
                                              unsigned short* __restrict__ out) {
  int i = blockIdx.x * 256 + threadIdx.x;  // 131072 total
  float v;
  if (i < 49152) v = w0[i];
  else if (i < 65536) v = w1[i - 49152];
  else if (i < 98304) v = w2[i - 65536];
  else v = w3[i - 98304];
  out[i] = f2bf(v);
}

// ---------------- LayerNorm: one wave per token, bf16 out ----------------
__global__ __launch_bounds__(256) void k_ln(const float* __restrict__ in,
                                            const float* __restrict__ w,
                                            const float* __restrict__ b,
                                            unsigned short* __restrict__ out) {
  int tok = blockIdx.x * 4 + (threadIdx.x >> 6);
  int lane = threadIdx.x & 63;
  float2 v = *(const float2*)&in[(size_t)tok * CDIM + lane * 2];
  float s = v.x + v.y;
#pragma unroll
  for (int m = 1; m < 64; m <<= 1) s += __shfl_xor(s, m);
  float mean = s * 0.0078125f;
  float dx = v.x - mean, dy = v.y - mean;
  float ss = dx * dx + dy * dy;
#pragma unroll
  for (int m = 1; m < 64; m <<= 1) ss += __shfl_xor(ss, m);
  float rs = rsqrtf(ss * 0.0078125f + 1e-5f);
  unsigned p0 = f2bf(dx * rs * w[lane * 2] + b[lane * 2]);
  unsigned p1 = f2bf(dy * rs * w[lane * 2 + 1] + b[lane * 2 + 1]);
  *(unsigned*)&out[(size_t)tok * CDIM + lane * 2] = p0 | (p1 << 16);
}

// ---------------- bf16 MFMA GEMM, LDS-staged, XOR-swizzled ----------------
// A:(M,K) bf16, W:(N,K) bf16. Block 256 thr = 4 waves (2x2), tile 128x64.
template <int ACT, int RES, int OUTBF>
__global__ __launch_bounds__(256) void k_gemm(const unsigned short* __restrict__ A,
                                              const unsigned short* __restrict__ W,
                                              const float* __restrict__ bias,
                                              const float* __restrict__ res,
                                              float* __restrict__ outF,
                                              unsigned short* __restrict__ outB,
                                              int M, int N, int K) {
  __shared__ short As[16384];  // 128 x 128 bf16, 16B-chunk swizzled
  __shared__ short Bs[8192];   // 64 x 128
  int tid = threadIdx.x;
  int lane = tid & 63, wave = tid >> 6;
  int wr = wave >> 1, wc = wave & 1;
  int r = lane & 15, kg = lane >> 4;
  int row0 = blockIdx.x * 128, col0 = blockIdx.y * 64;

  f32x4 acc[4][2] = {};

  for (int kt = 0; kt < K; kt += 128) {
#pragma unroll
    for (int it = 0; it < 8; ++it) {
      int idx = it * 4096 + tid * 16;  // byte
      int rr = idx >> 8;
      int cl = (idx >> 4) & 15;
      int gc = cl ^ (rr & 15);
      *(short8*)((char*)As + idx) =
          *(const short8*)(A + (size_t)(row0 + rr) * K + kt + gc * 8);
    }
#pragma unroll
    for (int it = 0; it < 4; ++it) {
      int idx = it * 4096 + tid * 16;
      int rr = idx >> 8;
      int cl = (idx >> 4) & 15;
      int gc = cl ^ (rr & 15);
      *(short8*)((char*)Bs + idx) =
          *(const short8*)(W + (size_t)(col0 + rr) * K + kt + gc * 8);
    }
    __syncthreads();
#pragma unroll
    for (int ks = 0; ks < 4; ++ks) {
      int c = ks * 4 + kg;
      short8 bfr[2];
#pragma unroll
      for (int ni = 0; ni < 2; ++ni) {
        int rr = wc * 32 + ni * 16 + r;
        bfr[ni] = *(const short8*)((char*)Bs + rr * 256 + ((c ^ (rr & 15)) * 16));
      }
#pragma unroll
      for (int mi = 0; mi < 4; ++mi) {
        int rr = wr * 64 + mi * 16 + r;
        short8 afr = *(const short8*)((char*)As + rr * 256 + ((c ^ (rr & 15)) * 16));
#pragma unroll
        for (int ni = 0; ni < 2; ++ni)
          acc[mi][ni] = __builtin_amdgcn_mfma_f32_16x16x32_bf16(afr, bfr[ni], acc[mi][ni], 0, 0, 0);
      }
    }
    __syncthreads();
  }

#pragma unroll
  for (int mi = 0; mi < 4; ++mi) {
#pragma unroll
    for (int ni = 0; ni < 2; ++ni) {
      int c = col0 + wc * 32 + ni * 16 + r;
      float bs = bias[c];
#pragma unroll
      for (int e = 0; e < 4; ++e) {
        int rr = row0 + wr * 64 + mi * 16 + kg * 4 + e;
        float o = acc[mi][ni][e] + bs;
        if (ACT) o = 0.5f * o * (1.0f + erff(o * 0.7071067811865475f));
        if (RES) o += res[(size_t)rr * N + c];
        if (OUTBF) outB[(size_t)rr * N + c] = f2bf(o);
        else outF[(size_t)rr * N + c] = o;
      }
    }
  }
}

// ---------------- MFMA 7x7 neighborhood attention ----------------
// Block = 8x8 query tile, 4 waves (wave = head). qkv bf16 [tok][384].
__global__ __launch_bounds__(256) void k_natt(const unsigned short* __restrict__ qkv,
                                              const float* __restrict__ rpb,
                                              unsigned short* __restrict__ out) {
  __shared__ unsigned short VT[27136];  // [nd=128][212] V^T, bf16
  __shared__ unsigned short U[4352];    // bounce 32x136 | P 4x64x16
  __shared__ unsigned short rpbs[676];
  int tid = threadIdx.x;
  int lane = tid & 63, head = tid >> 6;
  int r = lane & 15, kg = lane >> 4;
  int bd = blockIdx.z;
  int th = blockIdx.y * 8, tw = blockIdx.x * 8;
  int u0h = min(max(th - 3, 0), 34);
  int u0w = min(max(tw - 3, 0), 34);
  int base = bd * HW_;

  for (int i = tid; i < 676; i += 256) rpbs[i] = f2bf(rpb[i]);

  // ---- stage V^T via bounce buffer ----
  for (int pass = 0; pass < 7; ++pass) {
    int jl = tid >> 3;            // 0..31
    int j = pass * 32 + jl;
    int c0 = (tid & 7) * 16;
    short8 v0 = {0, 0, 0, 0, 0, 0, 0, 0}, v1 = v0;
    if (j < 196) {
      int kh = u0h + j / 14, kw = u0w + j % 14;
      const unsigned short* vp = qkv + (size_t)(base + kh * WDIM + kw) * 384 + 256 + c0;
      v0 = *(const short8*)vp;
      v1 = *(const short8*)(vp + 8);
    }
    __syncthreads();
    *(short8*)&U[jl * 136 + c0] = v0;
    *(short8*)&U[jl * 136 + c0 + 8] = v1;
    __syncthreads();
    int nd = tid & 127, jh = tid >> 7;
#pragma unroll
    for (int qq = 0; qq < 4; ++qq) {
      int j0 = pass * 32 + jh * 16 + qq * 4;
      if (j0 + 3 < 212) {
        int jb = jh * 16 + qq * 4;
        us4 pk;
        pk.x = U[(jb + 0) * 136 + nd];
        pk.y = U[(jb + 1) * 136 + nd];
        pk.z = U[(jb + 2) * 136 + nd];
        pk.w = U[(jb + 3) * 136 + nd];
        *(us4*)&VT[nd * 212 + j0] = pk;
      }
    }
  }
  __syncthreads();

  // per-lane query metadata + Q fragments (B-operand of swapped QK^T)
  int shq[4], swq[4], boff[4];
  short8 qf[4];
#pragma unroll
  for (int nt = 0; nt < 4; ++nt) {
    int q = nt * 16 + r;
    int hq = th + (q >> 3), wq = tw + (q & 7);
    shq[nt] = min(max(hq - 3, 0), 41);
    swq[nt] = min(max(wq - 3, 0), 41);
    boff[nt] = head * 169 + (6 - hq) * 13 + (6 - wq);
    qf[nt] = *(const short8*)(qkv + (size_t)(base + hq * WDIM + wq) * 384 + head * 32 + kg * 8);
  }

  f32x4 accO[4][2] = {};
  float rs[4] = {0.f, 0.f, 0.f, 0.f};
  unsigned short* Pp = U + head * 1024;  // per-wave private P chunk [64 q][16 keys]

  for (int jt = 0; jt < 13; ++jt) {
    // K fragment (A-operand): lane row = key
    int key = jt * 16 + r;
    int uk = min(key, 195);
    int ktok = base + (u0h + uk / 14) * WDIM + (u0w + uk % 14);
    short8 kf = *(const short8*)(qkv + (size_t)ktok * 384 + 128 + head * 32 + kg * 8);
    f32x4 zero = {0.f, 0.f, 0.f, 0.f};
    f32x4 sv[4];
#pragma unroll
    for (int nt = 0; nt < 4; ++nt)
      sv[nt] = __builtin_amdgcn_mfma_f32_16x16x32_bf16(kf, qf[nt], zero, 0, 0, 0);

    int k0 = jt * 16 + kg * 4;
    int kh0 = k0 / 14;
    int kw0 = k0 - kh0 * 14;
#pragma unroll
    for (int nt = 0; nt < 4; ++nt) {
      float p[4];
#pragma unroll
      for (int e = 0; e < 4; ++e) {
        int khh = kh0, kww = kw0 + e;
        if (kww >= 14) { kww -= 14; khh += 1; }
        int kh = u0h + khh, kw = u0w + kww;
        bool valid = ((unsigned)(kh - shq[nt]) <= 6u) && ((unsigned)(kw - swq[nt]) <= 6u);
        int bidx = boff[nt] + kh * 13 + kw;
        bidx = valid ? bidx : 0;
        float sc = sv[nt][e] * 0.17677669529663687f + bf2f(rpbs[bidx]);
        p[e] = valid ? __expf(sc) : 0.f;  // scores are tiny; no max-shift needed
      }
      rs[nt] += (p[0] + p[1]) + (p[2] + p[3]);
      us4 pk;
      pk.x = f2bf(p[0]); pk.y = f2bf(p[1]); pk.z = f2bf(p[2]); pk.w = f2bf(p[3]);
      *(us4*)&Pp[(nt * 16 + r) * 16 + kg * 4] = pk;
    }
    __syncthreads();
    // PV: O[q][d] += P(64x16) * V(16x32), 16x16x16 mfma
#pragma unroll
    for (int mi = 0; mi < 4; ++mi) {
      sh4 af = *(const sh4*)&Pp[(mi * 16 + r) * 16 + kg * 4];
#pragma unroll
      for (int ni = 0; ni < 2; ++ni) {
        sh4 bfv = *(const sh4*)&VT[(head * 32 + ni * 16 + r) * 212 + jt * 16 + kg * 4];
        asm("v_mfma_f32_16x16x16_bf16 %0, %1, %2, %0"
            : "+v"(accO[mi][ni]) : "v"(af), "v"(bfv));
      }
    }
  }

  // softmax denominators: reduce over key-groups, then redistribute
#pragma unroll
  for (int nt = 0; nt < 4; ++nt) {
    rs[nt] += __shfl_xor(rs[nt], 16);
    rs[nt] += __shfl_xor(rs[nt], 32);
  }
  int cr4 = kg * 4;
#pragma unroll
  for (int mi = 0; mi < 4; ++mi) {
#pragma unroll
    for (int e = 0; e < 4; ++e) {
      float inv = 1.f / __shfl(rs[mi], cr4 + e);
      int q = mi * 16 + cr4 + e;
      int tok = base + (th + (q >> 3)) * WDIM + (tw + (q & 7));
#pragma unroll
      for (int ni = 0; ni < 2; ++ni)
        out[(size_t)tok * CDIM + head * 32 + ni * 16 + r] = f2bf(accO[mi][ni][e] * inv);
    }
  }
}

extern "C" void kernel_launch(void* const* d_in, const int* in_sizes, int n_in,
                              void* d_out, int out_size, void* d_ws, size_t ws_size,
                              hipStream_t stream) {
  const float* x     = (const float*)d_in[0];
  const float* n1w   = (const float*)d_in[1];
  const float* n1b   = (const float*)d_in[2];
  const float* qkvw  = (const float*)d_in[3];
  const float* qkvb  = (const float*)d_in[4];
  const float* rpb   = (const float*)d_in[5];
  const float* projw = (const float*)d_in[6];
  const float* projb = (const float*)d_in[7];
  const float* n2w   = (const float*)d_in[8];
  const float* n2b   = (const float*)d_in[9];
  const float* fc1w  = (const float*)d_in[10];
  const float* fc1b  = (const float*)d_in[11];
  const float* fc2w  = (const float*)d_in[12];
  const float* fc2b  = (const float*)d_in[13];

  char* wsb = (char*)d_ws;
  float*          t0   = (float*)wsb;                         // 9,437,184 B
  float*          t1   = (float*)(wsb + 9437184);             // 9,437,184 B
  unsigned short* qkvB = (unsigned short*)(wsb + 18874368);   // 14,155,776 B
  unsigned short* attb = (unsigned short*)(wsb + 33030144);   // 4,718,592 B
  unsigned short* lnb  = (unsigned short*)(wsb + 37748736);   // 4,718,592 B
  unsigned short* h1b  = (unsigned short*)(wsb + 42467328);   // 9,437,184 B
  unsigned short* wbf  = (unsigned short*)(wsb + 51904512);   // 262,144 B
  float*          t2   = t0;  // t0 dead after proj residual

  k_w2bf<<<512, 256, 0, stream>>>(qkvw, projw, fc1w, fc2w, wbf);
  k_transpose_in<<<dim3(72, 4, 8), 256, 0, stream>>>(x, t0);
  k_ln<<<NTOK / 4, 256, 0, stream>>>(t0, n1w, n1b, lnb);
  k_gemm<0, 0, 1><<<dim3(144, 6), 256, 0, stream>>>(lnb, wbf, qkvb, nullptr,
                                                    nullptr, qkvB, NTOK, 384, 128);
  k_natt<<<dim3(6, 6, 8), 256, 0, stream>>>(qkvB, rpb, attb);
  k_gemm<0, 1, 0><<<dim3(144, 2), 256, 0, stream>>>(attb, wbf + 49152, projb, t0,
                                                    t1, nullptr, NTOK, 128, 128);
  k_ln<<<NTOK / 4, 256, 0, stream>>>(t1, n2w, n2b, lnb);
  k_gemm<1, 0, 1><<<dim3(144, 4), 256, 0, stream>>>(lnb, wbf + 65536, fc1b, nullptr,
                                                    nullptr, h1b, NTOK, 256, 128);
  k_gemm<0, 1, 0><<<dim3(144, 2), 256, 0, stream>>>(h1b, wbf + 98304, fc2b, t1,
                                                    t2, nullptr, NTOK, 128, 256);
  k_transpose_out<<<dim3(72, 4, 8), 256, 0, stream>>>(t2, (float*)d_out);
}